// Round 18
// baseline (182.676 us; speedup 1.0000x reference)
//
#include <hip/hip_runtime.h>

// StackedGIN: L=3 layers of { agg = h + scatter_sum(h[src] -> dst);
//   h = relu( relu(agg@W1+B1) @ W2 + B2 ) }, then out = h@Wc + Bc.
// N=50000, E=800000, D=96, C=10.
//
// R1: float4 gather.  R2: wave-scan slots.  R3: bf16 MFMA MLP.
// R4: h/agg bf16.  R5: prep fuse + fused classifier.  R6: no coop launch.
// R7 FAILED: agg-in-MLP capped occupancy.  R8: u16 csr.  R9: own zero.
// R10 NEUTRAL: fill line-ping-pong bound.  R11: bucketed CSR + XCD-
//     partitioned fill (236->189).  R12 FAILED: feature-split h (broke row
//     alignment, doubled requests, extra gaps).  R13: nt stores (186.6).
// R14/R15: mlp W from global, LDS 13.3KB (181.2).  R16: fill plain loads +
//     2048 grid (179.3; fill ~atomic-bound).
// R17: src-half phase-split aggregation. Buckets store lo-srcs (<N/2) at
//     slots [0,48) and hi-srcs at [48,96) (packed u16x2 cursor). aggb sums
//     lo sub-list then hi sub-list -> GPU-wide phase-coherent 4.8MB gather
//     working set (~ one XCD L2) per phase. Same rows/alignment/requests/
//     dispatches as R16 -> worst case neutral. Self/aggbuf loads nt.
// ws layout: hbuf(N*96 bf16) | aggbuf(N*96 bf16) | cursor(N) |
//            csr16(N*96 u16) | wt(6*9216 u16)

#define TPB 256
#define LDA 104  // bf16 elems per LDS row: 96 + 8 pad
#define BS 96    // csr bucket stride per node: lo at [0,48), hi at [48,96)
#define HC 48    // half-bucket capacity (Poisson(8): P(>=48) ~ 1e-25)

typedef __attribute__((ext_vector_type(8))) short bfrag8;
typedef __attribute__((ext_vector_type(8))) unsigned short u16x8;
typedef __attribute__((ext_vector_type(4))) float f32x4;
typedef __attribute__((ext_vector_type(4))) int i32x4;

__device__ inline unsigned short f2bf(float x) {  // RNE f32 -> bf16 bits
  unsigned int u = __float_as_uint(x);
  unsigned int r = u + 0x7FFFu + ((u >> 16) & 1u);
  return (unsigned short)(r >> 16);
}
__device__ inline float bf2f(unsigned short u) {
  return __uint_as_float(((unsigned int)u) << 16);
}

// jobs: [0,N) zero cursor; then weight transpose->bf16; then x->bf16.
__global__ __launch_bounds__(TPB) void prep_kernel(
    int* __restrict__ cursor, int N,
    const float* __restrict__ W1, const float* __restrict__ W2,
    unsigned short* __restrict__ wt,
    const float4* __restrict__ x4, u16x8* __restrict__ h8, int total8) {
  int t = blockIdx.x * TPB + threadIdx.x;
  if (t < N) { cursor[t] = 0; return; }
  t -= N;
  const int wjobs = 6 * 9216;
  if (t < wjobs) {
    int mat = t / 9216, idx = t - mat * 9216;
    int l = mat >> 1, which = mat & 1;
    int k = idx / 96, n = idx - k * 96;
    const float* src = (which ? W2 : W1) + (size_t)l * 9216;
    wt[(size_t)mat * 9216 + n * 96 + k] = f2bf(src[k * 96 + n]);
  } else {
    int u = t - wjobs;
    if (u < total8) {
      float4 a = x4[2 * u], b = x4[2 * u + 1];
      u16x8 o;
      o[0] = f2bf(a.x); o[1] = f2bf(a.y); o[2] = f2bf(a.z); o[3] = f2bf(a.w);
      o[4] = f2bf(b.x); o[5] = f2bf(b.y); o[6] = f2bf(b.z); o[7] = f2bf(b.w);
      h8[u] = o;
    }
  }
}

// XCD-partitioned bucketed fill. Buckets split by src half: src < halfN ->
// slots [0,HC) (cursor low u16), src >= halfN -> slots [HC,2HC) (high u16).
// One packed atomicAdd per edge (no carry: counts <= HC << 2^16).
__global__ __launch_bounds__(TPB) void fill_kernel(const int* __restrict__ src,
                                                   const int* __restrict__ dst,
                                                   int* __restrict__ cursor,
                                                   unsigned short* __restrict__ csr16,
                                                   int N, int E, int halfN) {
  const int g = blockIdx.x & 7;
  const int bid = blockIdx.x >> 3;
  const int nblk = gridDim.x >> 3;
  const int chunk = (N + 7) >> 3;
  const int lo = g * chunk;
  const unsigned span = (unsigned)((N - lo < chunk) ? (N - lo) : chunk);
  const int gsz = nblk * TPB;
  const int E8 = E >> 3;
  for (int t = bid * TPB + threadIdx.x; t < E8; t += gsz) {
    int base = 8 * t;
    i32x4 da = *reinterpret_cast<const i32x4*>(dst + base);
    i32x4 db = *reinterpret_cast<const i32x4*>(dst + base + 4);
    bool m0 = (unsigned)(da[0] - lo) < span;
    bool m1 = (unsigned)(da[1] - lo) < span;
    bool m2 = (unsigned)(da[2] - lo) < span;
    bool m3 = (unsigned)(da[3] - lo) < span;
    bool m4 = (unsigned)(db[0] - lo) < span;
    bool m5 = (unsigned)(db[1] - lo) < span;
    bool m6 = (unsigned)(db[2] - lo) < span;
    bool m7 = (unsigned)(db[3] - lo) < span;
    if (m0 | m1 | m2 | m3) {
      i32x4 sa = *reinterpret_cast<const i32x4*>(src + base);
#pragma unroll
      for (int u = 0; u < 4; u++) {
        bool m = (u == 0) ? m0 : (u == 1) ? m1 : (u == 2) ? m2 : m3;
        if (m) {
          int d = da[u], s = sa[u];
          bool hi = s >= halfN;
          int prev = atomicAdd(&cursor[d], hi ? 0x10000 : 1);
          int slot = hi ? (HC + (prev >> 16)) : (prev & 0xFFFF);
          csr16[(size_t)d * BS + slot] = (unsigned short)s;
        }
      }
    }
    if (m4 | m5 | m6 | m7) {
      i32x4 sb = *reinterpret_cast<const i32x4*>(src + base + 4);
#pragma unroll
      for (int u = 0; u < 4; u++) {
        bool m = (u == 0) ? m4 : (u == 1) ? m5 : (u == 2) ? m6 : m7;
        if (m) {
          int d = db[u], s = sb[u];
          bool hi = s >= halfN;
          int prev = atomicAdd(&cursor[d], hi ? 0x10000 : 1);
          int slot = hi ? (HC + (prev >> 16)) : (prev & 0xFFFF);
          csr16[(size_t)d * BS + slot] = (unsigned short)s;
        }
      }
    }
  }
  if (blockIdx.x == 0 && threadIdx.x == 0) {
    for (int e = E8 * 8; e < E; e++) {
      int d = dst[e], s = src[e];
      bool hi = s >= halfN;
      int prev = atomicAdd(&cursor[d], hi ? 0x10000 : 1);
      int slot = hi ? (HC + (prev >> 16)) : (prev & 0xFFFF);
      csr16[(size_t)d * BS + slot] = (unsigned short)s;
    }
  }
}

// Sum gathers over bucket sub-range [jb, je); jb is 8-aligned.
__device__ inline void gather_range(const unsigned short* __restrict__ row,
                                    int jb, int je,
                                    const u16x8* __restrict__ hin8, int f,
                                    float acc[8]) {
  int j = jb;
  for (; j + 8 <= je; j += 8) {
    u16x8 idx = *reinterpret_cast<const u16x8*>(row + j);
    u16x8 v0 = hin8[(size_t)idx[0] * 12 + f];
    u16x8 v1 = hin8[(size_t)idx[1] * 12 + f];
    u16x8 v2 = hin8[(size_t)idx[2] * 12 + f];
    u16x8 v3 = hin8[(size_t)idx[3] * 12 + f];
    u16x8 v4 = hin8[(size_t)idx[4] * 12 + f];
    u16x8 v5 = hin8[(size_t)idx[5] * 12 + f];
    u16x8 v6 = hin8[(size_t)idx[6] * 12 + f];
    u16x8 v7 = hin8[(size_t)idx[7] * 12 + f];
#pragma unroll
    for (int k = 0; k < 8; k++)
      acc[k] += ((bf2f(v0[k]) + bf2f(v1[k])) + (bf2f(v2[k]) + bf2f(v3[k]))) +
                ((bf2f(v4[k]) + bf2f(v5[k])) + (bf2f(v6[k]) + bf2f(v7[k])));
  }
  if (j + 4 <= je) {
    int i0 = row[j], i1 = row[j + 1], i2 = row[j + 2], i3 = row[j + 3];
    u16x8 v0 = hin8[(size_t)i0 * 12 + f];
    u16x8 v1 = hin8[(size_t)i1 * 12 + f];
    u16x8 v2 = hin8[(size_t)i2 * 12 + f];
    u16x8 v3 = hin8[(size_t)i3 * 12 + f];
#pragma unroll
    for (int k = 0; k < 8; k++)
      acc[k] += (bf2f(v0[k]) + bf2f(v1[k])) + (bf2f(v2[k]) + bf2f(v3[k]));
    j += 4;
  }
  for (; j < je; j++) {
    u16x8 v = hin8[(size_t)row[j] * 12 + f];
#pragma unroll
    for (int k = 0; k < 8; k++) acc[k] += bf2f(v[k]);
  }
}

// agg[i] = h[i] + sum(lo sub-list) + sum(hi sub-list); the phase split keeps
// the GPU-wide gather working set at ~4.8MB per phase (L2-resident).
__global__ __launch_bounds__(TPB) void aggb_kernel(const u16x8* __restrict__ hin8,
                                                   u16x8* __restrict__ hout8,
                                                   const int* __restrict__ cursor,
                                                   const unsigned short* __restrict__ csr16,
                                                   int n) {
  int t = blockIdx.x * TPB + threadIdx.x;
  if (t >= n * 12) return;
  int i = t / 12;
  int f = t - i * 12;
  const unsigned short* row = csr16 + (size_t)i * BS;
  u16x8 self = __builtin_nontemporal_load(&hin8[t]);
  float acc[8];
#pragma unroll
  for (int k = 0; k < 8; k++) acc[k] = bf2f(self[k]);
  int c = cursor[i];
  int dlo = c & 0xFFFF;
  int dhi = c >> 16;
  gather_range(row, 0, dlo, hin8, f, acc);        // phase 1: srcs < N/2
  gather_range(row, HC, HC + dhi, hin8, f, acc);  // phase 2: srcs >= N/2
  u16x8 o;
#pragma unroll
  for (int k = 0; k < 8; k++) o[k] = f2bf(acc[k]);
  __builtin_nontemporal_store(o, &hout8[t]);
}

// h = relu( relu(agg@W1+B1) @ W2 + B2 ); LAST computes out = h@Wc + Bc.
// B-fragments read directly from global wt (L2-broadcast across blocks);
// LDS holds only the A/Z tile -> 13.3KB, 8 blocks/CU.
template <bool LAST>
__global__ __launch_bounds__(TPB) void mlp_mfma_kernel(
    const u16x8* __restrict__ in8, const unsigned short* __restrict__ wt1,
    const unsigned short* __restrict__ wt2, const float* __restrict__ B1,
    const float* __restrict__ B2, unsigned short* __restrict__ out,
    const float* __restrict__ Wc, const float* __restrict__ Bc,
    float* __restrict__ outf, int nrows) {
  __shared__ unsigned short A_lds[64 * LDA];   // A tile, later Z tile
  const int tid = threadIdx.x;
  const int row0 = blockIdx.x * 64;

  // stage A (already bf16), rows [row0, row0+64)
  for (int t = tid; t < 64 * 12; t += TPB) {
    int r = t / 12, c8 = t - r * 12;
    int gr = row0 + r;
    u16x8 v = {};
    if (gr < nrows) v = in8[(size_t)gr * 12 + c8];
    *reinterpret_cast<u16x8*>(&A_lds[r * LDA + 8 * c8]) = v;
  }
  __syncthreads();

  const int lane = tid & 63;
  const int w = tid >> 6;     // wave id: rows [16w, 16w+16)
  const int nl = lane & 15;   // frag row (A) / col (B,D)
  const int q = lane >> 4;    // k-quarter
  const int arow = 16 * w + nl;

  bfrag8 afrag[3];
#pragma unroll
  for (int s = 0; s < 3; s++)
    afrag[s] = *reinterpret_cast<const bfrag8*>(&A_lds[arow * LDA + 32 * s + 8 * q]);

  // GEMM1 -> relu -> Z (bf16) into this wave's own A stripe (no barrier needed)
#pragma unroll
  for (int cb = 0; cb < 6; cb++) {
    f32x4 acc = {0.f, 0.f, 0.f, 0.f};
#pragma unroll
    for (int s = 0; s < 3; s++) {
      bfrag8 bfr = *reinterpret_cast<const bfrag8*>(
          wt1 + (size_t)(16 * cb + nl) * 96 + 32 * s + 8 * q);
      acc = __builtin_amdgcn_mfma_f32_16x16x32_bf16(afrag[s], bfr, acc, 0, 0, 0);
    }
    float b = B1[16 * cb + nl];
#pragma unroll
    for (int i = 0; i < 4; i++) {
      int m = 16 * w + 4 * q + i;
      A_lds[m * LDA + 16 * cb + nl] = f2bf(fmaxf(acc[i] + b, 0.f));
    }
  }

  bfrag8 zfrag[3];
#pragma unroll
  for (int s = 0; s < 3; s++)
    zfrag[s] = *reinterpret_cast<const bfrag8*>(&A_lds[arow * LDA + 32 * s + 8 * q]);

  float oacc[40];  // LAST only: per-lane partial out[i][c], static-indexed
#pragma unroll
  for (int t2 = 0; t2 < 40; t2++) oacc[t2] = 0.f;

#pragma unroll
  for (int cb = 0; cb < 6; cb++) {
    f32x4 acc = {0.f, 0.f, 0.f, 0.f};
#pragma unroll
    for (int s = 0; s < 3; s++) {
      bfrag8 bfr = *reinterpret_cast<const bfrag8*>(
          wt2 + (size_t)(16 * cb + nl) * 96 + 32 * s + 8 * q);
      acc = __builtin_amdgcn_mfma_f32_16x16x32_bf16(zfrag[s], bfr, acc, 0, 0, 0);
    }
    float b = B2[16 * cb + nl];
#pragma unroll
    for (int i = 0; i < 4; i++) {
      float hv = fmaxf(acc[i] + b, 0.f);
      if (!LAST) {
        int m = 16 * w + 4 * q + i;
        int gr = row0 + m;
        if (gr < nrows)
          __builtin_nontemporal_store(f2bf(hv), &out[(size_t)gr * 96 + 16 * cb + nl]);
      } else {
#pragma unroll
        for (int c = 0; c < 10; c++)
          oacc[i * 10 + c] += hv * Wc[(16 * cb + nl) * 10 + c];
      }
    }
  }

  if (LAST) {
    // reduce over the 16 nl-lanes within each q-group
#pragma unroll
    for (int m = 1; m < 16; m <<= 1) {
#pragma unroll
      for (int t2 = 0; t2 < 40; t2++) oacc[t2] += __shfl_xor(oacc[t2], m, 64);
    }
#pragma unroll
    for (int i = 0; i < 4; i++) {
      int gr = row0 + 16 * w + 4 * q + i;
      if (gr < nrows && nl < 10) {
        float v = 0.f;
#pragma unroll
        for (int c = 0; c < 10; c++)
          if (nl == c) v = oacc[i * 10 + c];
        __builtin_nontemporal_store(v + Bc[nl], &outf[(size_t)gr * 10 + nl]);
      }
    }
  }
}

extern "C" void kernel_launch(void* const* d_in, const int* in_sizes, int n_in,
                              void* d_out, int out_size, void* d_ws, size_t ws_size,
                              hipStream_t stream) {
  const float* x  = (const float*)d_in[0];
  const int*   ei = (const int*)d_in[1];
  const float* W1 = (const float*)d_in[2];
  const float* B1 = (const float*)d_in[3];
  const float* W2 = (const float*)d_in[4];
  const float* B2 = (const float*)d_in[5];
  const float* Wc = (const float*)d_in[6];
  const float* Bc = (const float*)d_in[7];
  float* out = (float*)d_out;

  const int N = in_sizes[0] / 96;
  const int E = in_sizes[1] / 2;
  const int* src = ei;       // edge_index[0]
  const int* dst = ei + E;   // edge_index[1]

  unsigned short* hbuf   = (unsigned short*)d_ws;        // N*96 bf16
  unsigned short* aggbuf = hbuf + (size_t)N * 96;        // N*96 bf16
  int* cursor = (int*)(aggbuf + (size_t)N * 96);         // N packed u16x2
  unsigned short* csr16 = (unsigned short*)(cursor + N); // N*BS u16
  unsigned short* wt    = csr16 + (size_t)N * BS;        // 6*9216 u16

  const int total8 = N * 12;
  const int prep_jobs = N + 6 * 9216 + total8;
  prep_kernel<<<(prep_jobs + TPB - 1) / TPB, TPB, 0, stream>>>(
      cursor, N, W1, W2, wt, (const float4*)x, (u16x8*)hbuf, total8);

  fill_kernel<<<2048, TPB, 0, stream>>>(src, dst, cursor, csr16, N, E, N / 2);

  for (int l = 0; l < 3; l++) {
    aggb_kernel<<<((N * 12) + TPB - 1) / TPB, TPB, 0, stream>>>(
        (const u16x8*)hbuf, (u16x8*)aggbuf, cursor, csr16, N);
    const unsigned short* wt1 = wt + (size_t)(l * 2) * 9216;
    const unsigned short* wt2 = wt + (size_t)(l * 2 + 1) * 9216;
    const float* b1 = B1 + (size_t)l * 96;
    const float* b2 = B2 + (size_t)l * 96;
    if (l < 2)
      mlp_mfma_kernel<false><<<(N + 63) / 64, TPB, 0, stream>>>(
          (const u16x8*)aggbuf, wt1, wt2, b1, b2, hbuf, Wc, Bc, out, N);
    else
      mlp_mfma_kernel<true><<<(N + 63) / 64, TPB, 0, stream>>>(
          (const u16x8*)aggbuf, wt1, wt2, b1, b2, hbuf, Wc, Bc, out, N);
  }
}

// Round 19
// 178.955 us; speedup vs baseline: 1.0208x; 1.0208x over previous
//
#include <hip/hip_runtime.h>

// StackedGIN: L=3 layers of { agg = h + scatter_sum(h[src] -> dst);
//   h = relu( relu(agg@W1+B1) @ W2 + B2 ) }, then out = h@Wc + Bc.
// N=50000, E=800000, D=96, C=10.
//
// R1: float4 gather.  R2: wave-scan slots.  R3: bf16 MFMA MLP.
// R4: h/agg bf16.  R5: prep fuse + fused classifier.  R6: no coop launch.
// R7 FAILED: agg-in-MLP capped occupancy.  R8: u16 csr.  R9: own zero.
// R10 NEUTRAL: fill line-ping-pong bound.  R11: bucketed CSR + XCD-
//     partitioned fill (236->189).  R12 FAILED: feature-split h.
// R13: nt stores (186.6).  R14/R15: mlp W from global (181.2).
// R16: fill plain loads + 2048 grid (179.3).
// R17 FAILED (reverted): src-half phase-split agg — per-XCD L2s must each
//     replicate the "phase working set" (>4MB) + blocks drift out of phase
//     + BS=96 widened fill's write span. 25us/layer = random-gather floor.
// R18: R16 base; prep's streaming conversions (wt, x->bf16) moved INTO the
//     fill kernel as extra blocks (fill is atomic-bound, VALU 4%, BW 18% ->
//     conversions ride free); cursor zero split into a 2us kernel.
// ws layout: hbuf(N*96 bf16) | aggbuf(N*96 bf16) | cursor(N) |
//            csr16(N*64 u16) | wt(6*9216 u16)

#define TPB 256
#define LDA 104    // bf16 elems per LDS row: 96 + 8 pad
#define BS 64      // csr bucket stride per node
#define FILLB 2048 // fill blocks (first FILLB blocks of fillprep)

typedef __attribute__((ext_vector_type(8))) short bfrag8;
typedef __attribute__((ext_vector_type(8))) unsigned short u16x8;
typedef __attribute__((ext_vector_type(4))) float f32x4;
typedef __attribute__((ext_vector_type(4))) int i32x4;

__device__ inline unsigned short f2bf(float x) {  // RNE f32 -> bf16 bits
  unsigned int u = __float_as_uint(x);
  unsigned int r = u + 0x7FFFu + ((u >> 16) & 1u);
  return (unsigned short)(r >> 16);
}
__device__ inline float bf2f(unsigned short u) {
  return __uint_as_float(((unsigned int)u) << 16);
}

__global__ __launch_bounds__(TPB) void zero_kernel(int* __restrict__ p, int n) {
  int i = blockIdx.x * TPB + threadIdx.x;
  if (i < n) p[i] = 0;
}

// Blocks [0,FILLB): XCD-partitioned bucketed fill (group g=blockIdx&7 owns
// dst range; every group streams all edges, L3-served; cursor/csr lines
// single-XCD). Blocks [FILLB,...): weight transpose->bf16 and x->bf16
// streaming jobs (ride in fill's atomic-latency shadow).
__global__ __launch_bounds__(TPB) void fillprep_kernel(
    const int* __restrict__ src, const int* __restrict__ dst,
    int* __restrict__ cursor, unsigned short* __restrict__ csr16,
    int N, int E,
    const float* __restrict__ W1, const float* __restrict__ W2,
    unsigned short* __restrict__ wt,
    const float4* __restrict__ x4, u16x8* __restrict__ h8, int total8) {
  if (blockIdx.x < FILLB) {
    const int g = blockIdx.x & 7;
    const int bid = blockIdx.x >> 3;
    const int nblk = FILLB >> 3;
    const int chunk = (N + 7) >> 3;
    const int lo = g * chunk;
    const unsigned span = (unsigned)((N - lo < chunk) ? (N - lo) : chunk);
    const int gsz = nblk * TPB;
    const int E8 = E >> 3;
    for (int t = bid * TPB + threadIdx.x; t < E8; t += gsz) {
      int base = 8 * t;
      i32x4 da = *reinterpret_cast<const i32x4*>(dst + base);
      i32x4 db = *reinterpret_cast<const i32x4*>(dst + base + 4);
      bool m0 = (unsigned)(da[0] - lo) < span;
      bool m1 = (unsigned)(da[1] - lo) < span;
      bool m2 = (unsigned)(da[2] - lo) < span;
      bool m3 = (unsigned)(da[3] - lo) < span;
      bool m4 = (unsigned)(db[0] - lo) < span;
      bool m5 = (unsigned)(db[1] - lo) < span;
      bool m6 = (unsigned)(db[2] - lo) < span;
      bool m7 = (unsigned)(db[3] - lo) < span;
      if (m0 | m1 | m2 | m3) {
        i32x4 sa = *reinterpret_cast<const i32x4*>(src + base);
        if (m0) {
          int slot = atomicAdd(&cursor[da[0]], 1);
          csr16[(size_t)da[0] * BS + slot] = (unsigned short)sa[0];
        }
        if (m1) {
          int slot = atomicAdd(&cursor[da[1]], 1);
          csr16[(size_t)da[1] * BS + slot] = (unsigned short)sa[1];
        }
        if (m2) {
          int slot = atomicAdd(&cursor[da[2]], 1);
          csr16[(size_t)da[2] * BS + slot] = (unsigned short)sa[2];
        }
        if (m3) {
          int slot = atomicAdd(&cursor[da[3]], 1);
          csr16[(size_t)da[3] * BS + slot] = (unsigned short)sa[3];
        }
      }
      if (m4 | m5 | m6 | m7) {
        i32x4 sb = *reinterpret_cast<const i32x4*>(src + base + 4);
        if (m4) {
          int slot = atomicAdd(&cursor[db[0]], 1);
          csr16[(size_t)db[0] * BS + slot] = (unsigned short)sb[0];
        }
        if (m5) {
          int slot = atomicAdd(&cursor[db[1]], 1);
          csr16[(size_t)db[1] * BS + slot] = (unsigned short)sb[1];
        }
        if (m6) {
          int slot = atomicAdd(&cursor[db[2]], 1);
          csr16[(size_t)db[2] * BS + slot] = (unsigned short)sb[2];
        }
        if (m7) {
          int slot = atomicAdd(&cursor[db[3]], 1);
          csr16[(size_t)db[3] * BS + slot] = (unsigned short)sb[3];
        }
      }
    }
    // tail (E not divisible by 8)
    if (blockIdx.x == 0 && threadIdx.x == 0) {
      for (int e = E8 * 8; e < E; e++) {
        int d = dst[e];
        int slot = atomicAdd(&cursor[d], 1);
        csr16[(size_t)d * BS + slot] = (unsigned short)src[e];
      }
    }
    return;
  }
  // conversion blocks
  int t = (blockIdx.x - FILLB) * TPB + threadIdx.x;
  const int wjobs = 6 * 9216;
  if (t < wjobs) {
    int mat = t / 9216, idx = t - mat * 9216;
    int l = mat >> 1, which = mat & 1;
    int k = idx / 96, n = idx - k * 96;
    const float* s = (which ? W2 : W1) + (size_t)l * 9216;
    wt[(size_t)mat * 9216 + n * 96 + k] = f2bf(s[k * 96 + n]);
  } else {
    int u = t - wjobs;
    if (u < total8) {
      float4 a = x4[2 * u], b = x4[2 * u + 1];
      u16x8 o;
      o[0] = f2bf(a.x); o[1] = f2bf(a.y); o[2] = f2bf(a.z); o[3] = f2bf(a.w);
      o[4] = f2bf(b.x); o[5] = f2bf(b.y); o[6] = f2bf(b.z); o[7] = f2bf(b.w);
      h8[u] = o;
    }
  }
}

// agg[i][c8] = h[i][c8] + sum_{j<deg[i]} h[csr[i*BS+j]][c8]; bf16 in/out,
// f32 accumulate. 12 threads/node; 8 neighbor indices loaded per u16x8.
__global__ __launch_bounds__(TPB) void aggb_kernel(const u16x8* __restrict__ hin8,
                                                   u16x8* __restrict__ hout8,
                                                   const int* __restrict__ deg,
                                                   const unsigned short* __restrict__ csr16,
                                                   int n) {
  int t = blockIdx.x * TPB + threadIdx.x;
  if (t >= n * 12) return;
  int i = t / 12;
  int f = t - i * 12;
  const unsigned short* row = csr16 + (size_t)i * BS;
  u16x8 self = hin8[t];
  float acc[8];
#pragma unroll
  for (int k = 0; k < 8; k++) acc[k] = bf2f(self[k]);
  int e = deg[i];
  int j = 0;
  for (; j + 8 <= e; j += 8) {
    u16x8 idx = *reinterpret_cast<const u16x8*>(row + j);
    u16x8 v0 = hin8[(size_t)idx[0] * 12 + f];
    u16x8 v1 = hin8[(size_t)idx[1] * 12 + f];
    u16x8 v2 = hin8[(size_t)idx[2] * 12 + f];
    u16x8 v3 = hin8[(size_t)idx[3] * 12 + f];
    u16x8 v4 = hin8[(size_t)idx[4] * 12 + f];
    u16x8 v5 = hin8[(size_t)idx[5] * 12 + f];
    u16x8 v6 = hin8[(size_t)idx[6] * 12 + f];
    u16x8 v7 = hin8[(size_t)idx[7] * 12 + f];
#pragma unroll
    for (int k = 0; k < 8; k++)
      acc[k] += ((bf2f(v0[k]) + bf2f(v1[k])) + (bf2f(v2[k]) + bf2f(v3[k]))) +
                ((bf2f(v4[k]) + bf2f(v5[k])) + (bf2f(v6[k]) + bf2f(v7[k])));
  }
  if (j + 4 <= e) {
    int i0 = row[j], i1 = row[j + 1], i2 = row[j + 2], i3 = row[j + 3];
    u16x8 v0 = hin8[(size_t)i0 * 12 + f];
    u16x8 v1 = hin8[(size_t)i1 * 12 + f];
    u16x8 v2 = hin8[(size_t)i2 * 12 + f];
    u16x8 v3 = hin8[(size_t)i3 * 12 + f];
#pragma unroll
    for (int k = 0; k < 8; k++)
      acc[k] += (bf2f(v0[k]) + bf2f(v1[k])) + (bf2f(v2[k]) + bf2f(v3[k]));
    j += 4;
  }
  for (; j < e; j++) {
    u16x8 v = hin8[(size_t)row[j] * 12 + f];
#pragma unroll
    for (int k = 0; k < 8; k++) acc[k] += bf2f(v[k]);
  }
  u16x8 o;
#pragma unroll
  for (int k = 0; k < 8; k++) o[k] = f2bf(acc[k]);
  __builtin_nontemporal_store(o, &hout8[t]);
}

// h = relu( relu(agg@W1+B1) @ W2 + B2 ); LAST computes out = h@Wc + Bc.
// B-fragments read directly from global wt (L2-broadcast across blocks);
// LDS holds only the A/Z tile -> 13.3KB, 8 blocks/CU.
template <bool LAST>
__global__ __launch_bounds__(TPB) void mlp_mfma_kernel(
    const u16x8* __restrict__ in8, const unsigned short* __restrict__ wt1,
    const unsigned short* __restrict__ wt2, const float* __restrict__ B1,
    const float* __restrict__ B2, unsigned short* __restrict__ out,
    const float* __restrict__ Wc, const float* __restrict__ Bc,
    float* __restrict__ outf, int nrows) {
  __shared__ unsigned short A_lds[64 * LDA];   // A tile, later Z tile
  const int tid = threadIdx.x;
  const int row0 = blockIdx.x * 64;

  // stage A (already bf16), rows [row0, row0+64)
  for (int t = tid; t < 64 * 12; t += TPB) {
    int r = t / 12, c8 = t - r * 12;
    int gr = row0 + r;
    u16x8 v = {};
    if (gr < nrows) v = in8[(size_t)gr * 12 + c8];
    *reinterpret_cast<u16x8*>(&A_lds[r * LDA + 8 * c8]) = v;
  }
  __syncthreads();

  const int lane = tid & 63;
  const int w = tid >> 6;     // wave id: rows [16w, 16w+16)
  const int nl = lane & 15;   // frag row (A) / col (B,D)
  const int q = lane >> 4;    // k-quarter
  const int arow = 16 * w + nl;

  bfrag8 afrag[3];
#pragma unroll
  for (int s = 0; s < 3; s++)
    afrag[s] = *reinterpret_cast<const bfrag8*>(&A_lds[arow * LDA + 32 * s + 8 * q]);

  // GEMM1 -> relu -> Z (bf16) into this wave's own A stripe (no barrier needed)
#pragma unroll
  for (int cb = 0; cb < 6; cb++) {
    f32x4 acc = {0.f, 0.f, 0.f, 0.f};
#pragma unroll
    for (int s = 0; s < 3; s++) {
      bfrag8 bfr = *reinterpret_cast<const bfrag8*>(
          wt1 + (size_t)(16 * cb + nl) * 96 + 32 * s + 8 * q);
      acc = __builtin_amdgcn_mfma_f32_16x16x32_bf16(afrag[s], bfr, acc, 0, 0, 0);
    }
    float b = B1[16 * cb + nl];
#pragma unroll
    for (int i = 0; i < 4; i++) {
      int m = 16 * w + 4 * q + i;
      A_lds[m * LDA + 16 * cb + nl] = f2bf(fmaxf(acc[i] + b, 0.f));
    }
  }

  bfrag8 zfrag[3];
#pragma unroll
  for (int s = 0; s < 3; s++)
    zfrag[s] = *reinterpret_cast<const bfrag8*>(&A_lds[arow * LDA + 32 * s + 8 * q]);

  float oacc[40];  // LAST only: per-lane partial out[i][c], static-indexed
#pragma unroll
  for (int t2 = 0; t2 < 40; t2++) oacc[t2] = 0.f;

#pragma unroll
  for (int cb = 0; cb < 6; cb++) {
    f32x4 acc = {0.f, 0.f, 0.f, 0.f};
#pragma unroll
    for (int s = 0; s < 3; s++) {
      bfrag8 bfr = *reinterpret_cast<const bfrag8*>(
          wt2 + (size_t)(16 * cb + nl) * 96 + 32 * s + 8 * q);
      acc = __builtin_amdgcn_mfma_f32_16x16x32_bf16(zfrag[s], bfr, acc, 0, 0, 0);
    }
    float b = B2[16 * cb + nl];
#pragma unroll
    for (int i = 0; i < 4; i++) {
      float hv = fmaxf(acc[i] + b, 0.f);
      if (!LAST) {
        int m = 16 * w + 4 * q + i;
        int gr = row0 + m;
        if (gr < nrows)
          __builtin_nontemporal_store(f2bf(hv), &out[(size_t)gr * 96 + 16 * cb + nl]);
      } else {
#pragma unroll
        for (int c = 0; c < 10; c++)
          oacc[i * 10 + c] += hv * Wc[(16 * cb + nl) * 10 + c];
      }
    }
  }

  if (LAST) {
    // reduce over the 16 nl-lanes within each q-group
#pragma unroll
    for (int m = 1; m < 16; m <<= 1) {
#pragma unroll
      for (int t2 = 0; t2 < 40; t2++) oacc[t2] += __shfl_xor(oacc[t2], m, 64);
    }
#pragma unroll
    for (int i = 0; i < 4; i++) {
      int gr = row0 + 16 * w + 4 * q + i;
      if (gr < nrows && nl < 10) {
        float v = 0.f;
#pragma unroll
        for (int c = 0; c < 10; c++)
          if (nl == c) v = oacc[i * 10 + c];
        __builtin_nontemporal_store(v + Bc[nl], &outf[(size_t)gr * 10 + nl]);
      }
    }
  }
}

extern "C" void kernel_launch(void* const* d_in, const int* in_sizes, int n_in,
                              void* d_out, int out_size, void* d_ws, size_t ws_size,
                              hipStream_t stream) {
  const float* x  = (const float*)d_in[0];
  const int*   ei = (const int*)d_in[1];
  const float* W1 = (const float*)d_in[2];
  const float* B1 = (const float*)d_in[3];
  const float* W2 = (const float*)d_in[4];
  const float* B2 = (const float*)d_in[5];
  const float* Wc = (const float*)d_in[6];
  const float* Bc = (const float*)d_in[7];
  float* out = (float*)d_out;

  const int N = in_sizes[0] / 96;
  const int E = in_sizes[1] / 2;
  const int* src = ei;       // edge_index[0]
  const int* dst = ei + E;   // edge_index[1]

  unsigned short* hbuf   = (unsigned short*)d_ws;        // N*96 bf16
  unsigned short* aggbuf = hbuf + (size_t)N * 96;        // N*96 bf16
  int* cursor = (int*)(aggbuf + (size_t)N * 96);         // N int (deg after fill)
  unsigned short* csr16 = (unsigned short*)(cursor + N); // N*BS u16
  unsigned short* wt    = csr16 + (size_t)N * BS;        // 6*9216 u16

  zero_kernel<<<(N + TPB - 1) / TPB, TPB, 0, stream>>>(cursor, N);

  const int total8 = N * 12;
  const int conv_jobs = 6 * 9216 + total8;
  const int conv_blocks = (conv_jobs + TPB - 1) / TPB;
  fillprep_kernel<<<FILLB + conv_blocks, TPB, 0, stream>>>(
      src, dst, cursor, csr16, N, E, W1, W2, wt, (const float4*)x,
      (u16x8*)hbuf, total8);

  for (int l = 0; l < 3; l++) {
    aggb_kernel<<<((N * 12) + TPB - 1) / TPB, TPB, 0, stream>>>(
        (const u16x8*)hbuf, (u16x8*)aggbuf, cursor, csr16, N);
    const unsigned short* wt1 = wt + (size_t)(l * 2) * 9216;
    const unsigned short* wt2 = wt + (size_t)(l * 2 + 1) * 9216;
    const float* b1 = B1 + (size_t)l * 96;
    const float* b2 = B2 + (size_t)l * 96;
    if (l < 2)
      mlp_mfma_kernel<false><<<(N + 63) / 64, TPB, 0, stream>>>(
          (const u16x8*)aggbuf, wt1, wt2, b1, b2, hbuf, Wc, Bc, out, N);
    else
      mlp_mfma_kernel<true><<<(N + 63) / 64, TPB, 0, stream>>>(
          (const u16x8*)aggbuf, wt1, wt2, b1, b2, hbuf, Wc, Bc, out, N);
  }
}